// Round 14
// baseline (589.258 us; speedup 1.0000x reference)
//
#include <hip/hip_runtime.h>
#include <hip/hip_bf16.h>

#define DM 2048
#define NTOK 8192
#define EPS 1e-6f

typedef __attribute__((ext_vector_type(8))) short short8;
typedef __attribute__((ext_vector_type(4))) short short4v;
typedef __attribute__((ext_vector_type(4))) float f32x4;
typedef __attribute__((ext_vector_type(16))) float f32x16;
typedef __attribute__((ext_vector_type(4))) unsigned int u32x4;

typedef const __attribute__((address_space(1))) void gvoid;
typedef __attribute__((address_space(3))) void lvoid;

static __device__ __forceinline__ unsigned short f2bf(float f) {
    unsigned u = __builtin_bit_cast(unsigned, f);
    unsigned r = u + 0x7FFFu + ((u >> 16) & 1u);
    return (unsigned short)(r >> 16);
}
static __device__ __forceinline__ float bf2f(unsigned short h) {
    return __builtin_bit_cast(float, (unsigned)h << 16);
}

// ---------------- prep: Wq/Wk/Wv transposes + 3 input norms (only what gemm_qkv needs)
// blocks [0,12288): wtrans z=bx>>12 in {Wq,Wk,Wv}; blocks [12288,36864): norms
__global__ __launch_bounds__(256) void prep(
        const float* __restrict__ Wq, const float* __restrict__ Wk,
        const float* __restrict__ Wv,
        unsigned short* __restrict__ Tq, unsigned short* __restrict__ Tk,
        unsigned short* __restrict__ Tv,
        const float* __restrict__ q, const float* __restrict__ k,
        const float* __restrict__ v,
        const float* __restrict__ qa, const float* __restrict__ qb,
        const float* __restrict__ ka, const float* __restrict__ kb,
        const float* __restrict__ va, const float* __restrict__ vb,
        unsigned short* __restrict__ oq, unsigned short* __restrict__ ok,
        unsigned short* __restrict__ ov, float isq) {
    const int bx = blockIdx.x;
    const int t = threadIdx.x;
    if (bx < 12288) {
        __shared__ float tile[32][33];
        const int z = bx >> 12, rem = bx & 4095;
        const float* W = z==0?Wq: z==1?Wk: Wv;
        unsigned short* Wt = z==0?Tq: z==1?Tk: Tv;
        const int perm = (z < 2) ? 1 : 0;
        const float ws = (z == 0) ? isq : 1.0f;
        const int bc = (rem & 63) * 32, bk = (rem >> 6) * 32;
        const int tc = t & 31, tr = t >> 5;
        #pragma unroll
        for (int i = 0; i < 4; ++i)
            tile[tr + i*8][tc] = W[(size_t)(bk + tr + i*8) * DM + bc + tc];
        __syncthreads();
        #pragma unroll
        for (int i = 0; i < 4; ++i) {
            const int c = bc + tr + i*8;
            const int pc = perm ? ((c & 127) * 16 + (c >> 7)) : c;
            Wt[(size_t)pc * DM + bk + tc] = f2bf(tile[tc][tr + i*8] * ws);
        }
    } else {
        const int rem = bx - 12288;
        const int z = rem >> 13, row = rem & 8191;
        const float* in    = z == 0 ? q  : z == 1 ? k  : v;
        const float* alpha = z == 0 ? qa : z == 1 ? ka : va;
        const float* beta  = z == 0 ? qb : z == 1 ? kb : vb;
        unsigned short* out = z == 0 ? oq : z == 1 ? ok : ov;

        const float* x = in + (size_t)row * DM + t * 8;
        float4 v0 = *(const float4*)(x);
        float4 v1 = *(const float4*)(x + 4);
        float s = (v0.x + v0.y) + (v0.z + v0.w) + (v1.x + v1.y) + (v1.z + v1.w);
        float ss = v0.x*v0.x + v0.y*v0.y + v0.z*v0.z + v0.w*v0.w
                 + v1.x*v1.x + v1.y*v1.y + v1.z*v1.z + v1.w*v1.w;
        #pragma unroll
        for (int m = 1; m < 64; m <<= 1) {
            s  += __shfl_xor(s, m);
            ss += __shfl_xor(ss, m);
        }
        __shared__ float red[8];
        const int wv = t >> 6, ln = t & 63;
        if (ln == 0) { red[wv] = s; red[4 + wv] = ss; }
        __syncthreads();
        s  = (red[0] + red[1]) + (red[2] + red[3]);
        ss = (red[4] + red[5]) + (red[6] + red[7]);
        const float mu = s * (1.0f / DM);
        float var = (ss - s * mu) * (1.0f / (DM - 1));
        var = fmaxf(var, 0.0f);
        const float scale = 1.0f / (sqrtf(var) + EPS);
        float4 a0 = *(const float4*)(alpha + t*8);
        float4 a1 = *(const float4*)(alpha + t*8 + 4);
        float4 b0 = *(const float4*)(beta + t*8);
        float4 b1 = *(const float4*)(beta + t*8 + 4);
        short8 o;
        o[0] = (short)f2bf(a0.x * (v0.x - mu) * scale + b0.x);
        o[1] = (short)f2bf(a0.y * (v0.y - mu) * scale + b0.y);
        o[2] = (short)f2bf(a0.z * (v0.z - mu) * scale + b0.z);
        o[3] = (short)f2bf(a0.w * (v0.w - mu) * scale + b0.w);
        o[4] = (short)f2bf(a1.x * (v1.x - mu) * scale + b1.x);
        o[5] = (short)f2bf(a1.y * (v1.y - mu) * scale + b1.y);
        o[6] = (short)f2bf(a1.z * (v1.z - mu) * scale + b1.z);
        o[7] = (short)f2bf(a1.w * (v1.w - mu) * scale + b1.w);
        *(short8*)(out + (size_t)row * DM + t * 8) = o;
    }
}

// ---------------- row norm (bf16 in) -> bf16 out
__global__ __launch_bounds__(256) void norm_rows_bf16(
        const unsigned short* __restrict__ in, const float* __restrict__ alpha,
        const float* __restrict__ beta, unsigned short* __restrict__ out) {
    const int row = blockIdx.x;
    const int t = threadIdx.x;
    short8 rv = *(const short8*)(in + (size_t)row * DM + t * 8);
    float xv[8];
    #pragma unroll
    for (int j = 0; j < 8; ++j) xv[j] = bf2f((unsigned short)rv[j]);
    float s = 0.f, ss = 0.f;
    #pragma unroll
    for (int j = 0; j < 8; ++j) { s += xv[j]; ss += xv[j]*xv[j]; }
    #pragma unroll
    for (int m = 1; m < 64; m <<= 1) {
        s  += __shfl_xor(s, m);
        ss += __shfl_xor(ss, m);
    }
    __shared__ float red[8];
    const int wv = t >> 6, ln = t & 63;
    if (ln == 0) { red[wv] = s; red[4 + wv] = ss; }
    __syncthreads();
    s  = (red[0] + red[1]) + (red[2] + red[3]);
    ss = (red[4] + red[5]) + (red[6] + red[7]);
    const float mu = s * (1.0f / DM);
    float var = (ss - s * mu) * (1.0f / (DM - 1));
    var = fmaxf(var, 0.0f);
    const float scale = 1.0f / (sqrtf(var) + EPS);
    short8 o;
    #pragma unroll
    for (int j = 0; j < 8; ++j) {
        const float av = alpha[t*8 + j], bv = beta[t*8 + j];
        o[j] = (short)f2bf(av * (xv[j] - mu) * scale + bv);
    }
    *(short8*)(out + (size_t)row * DM + t * 8) = o;
}

// ---------------- 256x256x64 GEMM core (r11 schedule)
#define BARRIER __builtin_amdgcn_s_barrier()
#define WAIT_LGKM0 asm volatile("s_waitcnt lgkmcnt(0)" ::: "memory")
#define VMCNT(n) asm volatile("s_waitcnt vmcnt(" #n ")" ::: "memory")
#define SCHED_FENCE __builtin_amdgcn_sched_barrier(0)

template<int EPI>
__device__ __forceinline__ void gemm_core(
        const unsigned short* __restrict__ A, const unsigned short* __restrict__ Bt,
        const float* __restrict__ bias, const float* __restrict__ residF,
        const unsigned short* __restrict__ residB,
        float* __restrict__ outF, unsigned short* __restrict__ outB, int biasPerm,
        float bscale, int blk) {
    __shared__ __align__(16) char lds[131072];
    char* ldsA = lds;
    char* ldsB = lds + 65536;

    const int t = threadIdx.x, l = t & 63, w = t >> 6;
    const int wm = w >> 2, wn = w & 3;

    const int xcd = blk & 7;
    const int j = blk >> 3;
    const int m0 = (xcd * 4 + (j & 3)) * 256;
    const int n0 = (j >> 2) * 256;

    const int rS = t >> 3;
    const int cS = ((t & 7) ^ (rS & 7)) * 8;
    const unsigned short* aSt = A  + (size_t)(m0 + rS) * 2048 + cS;
    const unsigned short* bSt = Bt + (size_t)(n0 + rS) * 2048 + cS;
    const int ldsStW = w * 1024;

    const int aRd = wm * 16384 + (l & 15) * 128;
    const int bRd = (wn >> 1) * 16384 + (wn & 1) * 8192 + (l & 15) * 128;
    const int ch0 = (((l >> 4) + 0) ^ (l & 7)) * 16;
    const int ch1 = (((l >> 4) + 4) ^ (l & 7)) * 16;

    short8 af[8][2], bf[4][2];
    f32x4 acc[8][4] = {};

#define STG_A(buf, h, kt) do { \
    __builtin_amdgcn_global_load_lds((gvoid*)(aSt + (size_t)((h)*128)*2048 + (kt)*64), \
        (lvoid*)(ldsA + (buf)*32768 + (h)*16384 + ldsStW), 16, 0, 0); \
    __builtin_amdgcn_global_load_lds((gvoid*)(aSt + (size_t)((h)*128+64)*2048 + (kt)*64), \
        (lvoid*)(ldsA + (buf)*32768 + (h)*16384 + 8192 + ldsStW), 16, 0, 0); \
} while(0)
#define STG_B(buf, h, kt) do { \
    __builtin_amdgcn_global_load_lds((gvoid*)(bSt + (size_t)((h)*128)*2048 + (kt)*64), \
        (lvoid*)(ldsB + (buf)*32768 + (h)*16384 + ldsStW), 16, 0, 0); \
    __builtin_amdgcn_global_load_lds((gvoid*)(bSt + (size_t)((h)*128+64)*2048 + (kt)*64), \
        (lvoid*)(ldsB + (buf)*32768 + (h)*16384 + 8192 + ldsStW), 16, 0, 0); \
} while(0)
#define RD_A(buf, mh) do { \
    _Pragma("unroll") for (int ml = 0; ml < 4; ++ml) { \
        af[(mh)*4+ml][0] = *(const short8*)(ldsA + (buf)*32768 + aRd + ((mh)*4+ml)*2048 + ch0); \
        af[(mh)*4+ml][1] = *(const short8*)(ldsA + (buf)*32768 + aRd + ((mh)*4+ml)*2048 + ch1); \
    } } while(0)
#define RD_B(buf, nh) do { \
    _Pragma("unroll") for (int nl = 0; nl < 2; ++nl) { \
        bf[(nh)*2+nl][0] = *(const short8*)(ldsB + (buf)*32768 + bRd + ((nh)*2+nl)*2048 + ch0); \
        bf[(nh)*2+nl][1] = *(const short8*)(ldsB + (buf)*32768 + bRd + ((nh)*2+nl)*2048 + ch1); \
    } } while(0)
#define MM_Q(mh, nh) do { \
    _Pragma("unroll") for (int ml = 0; ml < 4; ++ml) \
    _Pragma("unroll") for (int nl = 0; nl < 2; ++nl) { \
        acc[(mh)*4+ml][(nh)*2+nl] = __builtin_amdgcn_mfma_f32_16x16x32_bf16( \
            af[(mh)*4+ml][0], bf[(nh)*2+nl][0], acc[(mh)*4+ml][(nh)*2+nl], 0, 0, 0); \
        acc[(mh)*4+ml][(nh)*2+nl] = __builtin_amdgcn_mfma_f32_16x16x32_bf16( \
            af[(mh)*4+ml][1], bf[(nh)*2+nl][1], acc[(mh)*4+ml][(nh)*2+nl], 0, 0, 0); \
    } \
} while(0)

    STG_A(0, 0, 0); STG_A(0, 1, 0);
    STG_B(0, 0, 0); STG_B(0, 1, 0);
    STG_A(1, 0, 1); STG_A(1, 1, 1);
    VMCNT(4);
    BARRIER;

    #pragma unroll 1
    for (int i = 0; i < 16; ++i) {
        const int kt1 = 2*i + 1, k2 = 2*i + 2, k3 = 2*i + 3;
        const bool more = (i < 15);
        RD_A(0, 0); RD_A(0, 1); RD_B(0, 0);
        STG_B(1, 0, kt1); STG_B(1, 1, kt1);
        SCHED_FENCE;
        BARRIER; WAIT_LGKM0;
        __builtin_amdgcn_s_setprio(1);
        MM_Q(0, 0); MM_Q(1, 0);
        __builtin_amdgcn_s_setprio(0);
        BARRIER;
        RD_B(0, 1);
        if (more) { STG_A(0, 0, k2); STG_A(0, 1, k2); SCHED_FENCE; VMCNT(4); }
        else { SCHED_FENCE; VMCNT(0); }
        BARRIER; WAIT_LGKM0;
        __builtin_amdgcn_s_setprio(1);
        MM_Q(0, 1); MM_Q(1, 1);
        __builtin_amdgcn_s_setprio(0);
        BARRIER;
        RD_A(1, 0); RD_A(1, 1); RD_B(1, 0);
        if (more) { STG_B(0, 0, k2); STG_B(0, 1, k2); }
        SCHED_FENCE;
        BARRIER; WAIT_LGKM0;
        __builtin_amdgcn_s_setprio(1);
        MM_Q(0, 0); MM_Q(1, 0);
        __builtin_amdgcn_s_setprio(0);
        BARRIER;
        RD_B(1, 1);
        if (more) { STG_A(1, 0, k3); STG_A(1, 1, k3); SCHED_FENCE; VMCNT(4); }
        else { SCHED_FENCE; }
        BARRIER; WAIT_LGKM0;
        __builtin_amdgcn_s_setprio(1);
        MM_Q(0, 1); MM_Q(1, 1);
        __builtin_amdgcn_s_setprio(0);
        BARRIER;
    }

    unsigned short* cs = (unsigned short*)lds;   // [128][260] padded
    #pragma unroll 1
    for (int pass = 0; pass < 2; ++pass) {
        BARRIER;
        if (wm == pass) {
            #pragma unroll
            for (int ni = 0; ni < 4; ++ni) {
                const int col = wn*64 + ni*16 + (l & 15);
                const int gcol = n0 + col;
                const int cb = biasPerm ? ((gcol >> 4) + (gcol & 15) * 128) : gcol;
                const float bvv = bias[cb] * bscale;
                #pragma unroll
                for (int mi = 0; mi < 8; ++mi) {
                    #pragma unroll
                    for (int r = 0; r < 4; ++r) {
                        const int row = mi*16 + (l >> 4)*4 + r;
                        float vv = acc[mi][ni][r] + bvv;
                        if (EPI == 1) vv = fmaxf(vv, 0.0f);
                        cs[row*260 + col] = f2bf(vv);
                    }
                }
            }
        }
        BARRIER;
        #pragma unroll
        for (int s = 0; s < 8; ++s) {
            const int row = (t >> 5) + s*16;
            const int seg = t & 31;
            short8 pk = *(const short8*)(cs + row*260 + seg*8);
            const int grow = m0 + pass*128 + row;
            const size_t gb = (size_t)grow * 2048 + n0 + seg*8;
            if (EPI == 3) {
                float4 r0 = *(const float4*)(residF + gb);
                float4 r1 = *(const float4*)(residF + gb + 4);
                short8 o;
                o[0] = (short)f2bf(bf2f((unsigned short)pk[0]) + r0.x);
                o[1] = (short)f2bf(bf2f((unsigned short)pk[1]) + r0.y);
                o[2] = (short)f2bf(bf2f((unsigned short)pk[2]) + r0.z);
                o[3] = (short)f2bf(bf2f((unsigned short)pk[3]) + r0.w);
                o[4] = (short)f2bf(bf2f((unsigned short)pk[4]) + r1.x);
                o[5] = (short)f2bf(bf2f((unsigned short)pk[5]) + r1.y);
                o[6] = (short)f2bf(bf2f((unsigned short)pk[6]) + r1.z);
                o[7] = (short)f2bf(bf2f((unsigned short)pk[7]) + r1.w);
                *(short8*)(outB + gb) = o;
            } else if (EPI == 4) {
                short8 rb = *(const short8*)(residB + gb);
                float4 o0, o1;
                o0.x = bf2f((unsigned short)pk[0]) + bf2f((unsigned short)rb[0]);
                o0.y = bf2f((unsigned short)pk[1]) + bf2f((unsigned short)rb[1]);
                o0.z = bf2f((unsigned short)pk[2]) + bf2f((unsigned short)rb[2]);
                o0.w = bf2f((unsigned short)pk[3]) + bf2f((unsigned short)rb[3]);
                o1.x = bf2f((unsigned short)pk[4]) + bf2f((unsigned short)rb[4]);
                o1.y = bf2f((unsigned short)pk[5]) + bf2f((unsigned short)rb[5]);
                o1.z = bf2f((unsigned short)pk[6]) + bf2f((unsigned short)rb[6]);
                o1.w = bf2f((unsigned short)pk[7]) + bf2f((unsigned short)rb[7]);
                *(float4*)(outF + gb) = o0;
                *(float4*)(outF + gb + 4) = o1;
            } else {
                *(short8*)(outB + gb) = pk;
            }
        }
    }
#undef STG_A
#undef STG_B
#undef RD_A
#undef RD_B
#undef MM_Q
}

template<int EPI>
__global__ __launch_bounds__(512, 2) void gemm256(
        const unsigned short* __restrict__ A, const unsigned short* __restrict__ Bt,
        const float* __restrict__ bias, const float* __restrict__ residF,
        const unsigned short* __restrict__ residB,
        float* __restrict__ outF, unsigned short* __restrict__ outB, int biasPerm,
        float bscale) {
    gemm_core<EPI>(A, Bt, bias, residF, residB, outF, outB, biasPerm, bscale, blockIdx.x);
}

// fused Q/K/V projection (blocks 0..767) + Wo/W1/W2 transpose tail (blocks 768+).
// Tail results are consumed only by post-attn GEMMs -> ordering safe.
__global__ __launch_bounds__(512, 2) void gemm_qkv(
        const unsigned short* __restrict__ Aq, const unsigned short* __restrict__ Ak,
        const unsigned short* __restrict__ Av,
        const unsigned short* __restrict__ Bq, const unsigned short* __restrict__ Bk,
        const unsigned short* __restrict__ Bv,
        const float* __restrict__ bq, const float* __restrict__ bk,
        const float* __restrict__ bv,
        unsigned short* __restrict__ Oq, unsigned short* __restrict__ Ok,
        unsigned short* __restrict__ Ov,
        const float* __restrict__ Wo, const float* __restrict__ W1,
        const float* __restrict__ W2,
        unsigned short* __restrict__ To, unsigned short* __restrict__ T1,
        unsigned short* __restrict__ T2, float isq) {
    if (blockIdx.x < 768) {
        const int z = blockIdx.x >> 8;
        const int blk = blockIdx.x & 255;
        const unsigned short* A  = z == 0 ? Aq : z == 1 ? Ak : Av;
        const unsigned short* Bt = z == 0 ? Bq : z == 1 ? Bk : Bv;
        const float* bias        = z == 0 ? bq : z == 1 ? bk : bv;
        unsigned short* outB     = z == 0 ? Oq : z == 1 ? Ok : Ov;
        const int biasPerm = (z < 2) ? 1 : 0;
        const float bscale = (z == 0) ? isq : 1.0f;
        gemm_core<0>(A, Bt, bias, nullptr, nullptr, nullptr, outB, biasPerm, bscale, blk);
    } else {
        // two 32x32 transpose tiles per block (512 threads = 2 x 256)
        __shared__ float tile2[2][32][33];
        const int t = threadIdx.x;
        const int half = t >> 8, tl = t & 255;
        const int tid = (blockIdx.x - 768) * 2 + half;   // [0, 12288)
        const int z = tid >> 12, trem = tid & 4095;      // z: 0=Wo 1=W1 2=W2
        const float* W = z==0?Wo: z==1?W1: W2;
        unsigned short* Wt = z==0?To: z==1?T1: T2;
        const int bc = (trem & 63) * 32, bk = (trem >> 6) * 32;
        const int tc = tl & 31, tr = tl >> 5;
        #pragma unroll
        for (int i = 0; i < 4; ++i)
            tile2[half][tr + i*8][tc] = W[(size_t)(bk + tr + i*8) * DM + bc + tc];
        __syncthreads();
        #pragma unroll
        for (int i = 0; i < 4; ++i) {
            const int c = bc + tr + i*8;
            Wt[(size_t)c * DM + bk + tc] = f2bf(tile2[half][tc][tr + i*8]);
        }
    }
}

// ---------------- per-token attention, fully in-register (swapped QK^T + cvt_pk/permlane)
__global__ __launch_bounds__(256) void attn_tok(
        const unsigned short* __restrict__ Qt, const unsigned short* __restrict__ Kt,
        const unsigned short* __restrict__ Vp, unsigned short* __restrict__ Cc) {
    const int n = blockIdx.x;
    const int t = threadIdx.x, w = t >> 6, l = t & 63;
    const int q31 = l & 31, hi = l >> 5;
    __shared__ __align__(16) unsigned short c_s[16 * 132];

    const size_t tb = (size_t)n * DM;
    const short8 qf = *(const short8*)(Qt + tb + (w*32 + q31)*16 + hi*8);
    short8 kf[4];
    #pragma unroll
    for (int bt = 0; bt < 4; ++bt)
        kf[bt] = *(const short8*)(Kt + tb + (bt*32 + q31)*16 + hi*8);
    short8 vf[8];
    #pragma unroll
    for (int ks = 0; ks < 8; ++ks)
        vf[ks] = *(const short8*)(Vp + tb + (q31 & 15)*128 + ks*16 + hi*8);

    const f32x16 z = {};
    f32x16 sc[4];
    #pragma unroll
    for (int bt = 0; bt < 4; ++bt)
        sc[bt] = __builtin_amdgcn_mfma_f32_32x32x16_bf16(kf[bt], qf, z, 0, 0, 0);

    float m0 = sc[0][0], m1 = sc[1][0], m2 = sc[2][0], m3 = sc[3][0];
    #pragma unroll
    for (int r = 1; r < 16; ++r) {
        m0 = fmaxf(m0, sc[0][r]); m1 = fmaxf(m1, sc[1][r]);
        m2 = fmaxf(m2, sc[2][r]); m3 = fmaxf(m3, sc[3][r]);
    }
    float mx = fmaxf(fmaxf(m0, m1), fmaxf(m2, m3));
    { float a2 = mx, b2 = mx;
      asm volatile("v_permlane32_swap_b32 %0, %1" : "+v"(a2), "+v"(b2));
      mx = fmaxf(a2, b2); }

    float p[4][16];
    float s0 = 0.f, s1 = 0.f, s2 = 0.f, s3 = 0.f;
    #pragma unroll
    for (int r = 0; r < 16; ++r) {
        p[0][r] = __expf(sc[0][r] - mx); s0 += p[0][r];
        p[1][r] = __expf(sc[1][r] - mx); s1 += p[1][r];
        p[2][r] = __expf(sc[2][r] - mx); s2 += p[2][r];
        p[3][r] = __expf(sc[3][r] - mx); s3 += p[3][r];
    }
    float sm = (s0 + s1) + (s2 + s3);
    { float a2 = sm, b2 = sm;
      asm volatile("v_permlane32_swap_b32 %0, %1" : "+v"(a2), "+v"(b2));
      sm = a2 + b2; }
    const float inv = __builtin_amdgcn_rcpf(sm);
    #pragma unroll
    for (int bt = 0; bt < 4; ++bt)
        #pragma unroll
        for (int r = 0; r < 16; ++r)
            p[bt][r] *= inv;

    f32x16 acc = {};
    #pragma unroll
    for (int ks = 0; ks < 8; ++ks) {
        const int bt = ks >> 1, r0 = (ks & 1) * 8;
        unsigned X0, Y0, X1, Y1;
        asm("v_cvt_pk_bf16_f32 %0, %1, %2" : "=v"(X0) : "v"(p[bt][r0+0]), "v"(p[bt][r0+1]));
        asm("v_cvt_pk_bf16_f32 %0, %1, %2" : "=v"(Y0) : "v"(p[bt][r0+4]), "v"(p[bt][r0+5]));
        asm("v_cvt_pk_bf16_f32 %0, %1, %2" : "=v"(X1) : "v"(p[bt][r0+2]), "v"(p[bt][r0+3]));
        asm("v_cvt_pk_bf16_f32 %0, %1, %2" : "=v"(Y1) : "v"(p[bt][r0+6]), "v"(p[bt][r0+7]));
        asm volatile("v_permlane32_swap_b32 %0, %1" : "+v"(X0), "+v"(Y0));
        asm volatile("v_permlane32_swap_b32 %0, %1" : "+v"(X1), "+v"(Y1));
        u32x4 pw; pw[0] = X0; pw[1] = X1; pw[2] = Y0; pw[3] = Y1;
        const short8 paf = __builtin_bit_cast(short8, pw);
        acc = __builtin_amdgcn_mfma_f32_32x32x16_bf16(paf, vf[ks], acc, 0, 0, 0);
    }

    if (q31 < 16) {
        #pragma unroll
        for (int rp = 0; rp < 8; ++rp) {
            const int r = rp * 2;
            const int a = (r & 3) + 8 * (r >> 2) + 4 * hi;
            unsigned pk;
            asm("v_cvt_pk_bf16_f32 %0, %1, %2" : "=v"(pk) : "v"(acc[r]), "v"(acc[r+1]));
            *(unsigned*)((char*)c_s + q31*264 + (w*32 + a)*2) = pk;
        }
    }
    __syncthreads();
    *(short8*)(Cc + tb + t*8) = *(const short8*)((char*)c_s + (t >> 4)*264 + (t & 15)*16);
}

extern "C" void kernel_launch(void* const* d_in, const int* in_sizes, int n_in,
                              void* d_out, int out_size, void* d_ws, size_t ws_size,
                              hipStream_t stream) {
    (void)in_sizes; (void)n_in; (void)out_size; (void)ws_size;
    const float* q    = (const float*)d_in[0];
    const float* k    = (const float*)d_in[1];
    const float* v    = (const float*)d_in[2];
    const float* nq_a = (const float*)d_in[3];
    const float* nq_b = (const float*)d_in[4];
    const float* nk_a = (const float*)d_in[5];
    const float* nk_b = (const float*)d_in[6];
    const float* nv_a = (const float*)d_in[7];
    const float* nv_b = (const float*)d_in[8];
    const float* n2_a = (const float*)d_in[9];
    const float* n2_b = (const float*)d_in[10];
    const float* Wq   = (const float*)d_in[11];
    const float* bq   = (const float*)d_in[12];
    const float* Wk   = (const float*)d_in[13];
    const float* bk   = (const float*)d_in[14];
    const float* Wv   = (const float*)d_in[15];
    const float* bv   = (const float*)d_in[16];
    const float* Wo   = (const float*)d_in[17];
    const float* bo   = (const float*)d_in[18];
    const float* W1   = (const float*)d_in[19];
    const float* b1   = (const float*)d_in[20];
    const float* W2   = (const float*)d_in[21];
    const float* b2   = (const float*)d_in[22];

    char* ws = (char*)d_ws;
    const size_t MB = 1024 * 1024;
    unsigned short* buf0 = (unsigned short*)(ws);            // qn, later concat
    unsigned short* QtB  = (unsigned short*)(ws + 32*MB);
    unsigned short* KtB  = (unsigned short*)(ws + 64*MB);
    unsigned short* VpB  = (unsigned short*)(ws + 96*MB);
    unsigned short* Wqt  = (unsigned short*)(ws + 128*MB);
    unsigned short* Wkt  = (unsigned short*)(ws + 136*MB);
    unsigned short* Wvt  = (unsigned short*)(ws + 144*MB);
    unsigned short* Wot  = (unsigned short*)(ws + 152*MB);
    unsigned short* W1t  = (unsigned short*)(ws + 160*MB);
    unsigned short* W2t  = (unsigned short*)(ws + 168*MB);
    unsigned short* x2   = QtB;   // after Q consumed
    unsigned short* h1   = KtB;   // after K consumed
    unsigned short* xb   = VpB;   // bf16 residual stream, after V consumed
    float* x = (float*)d_out;     // final f32 output
    // d_out (64MB) doubles as kn/vn scratch until FF2's final write
    unsigned short* knB = (unsigned short*)d_out;            // 32MB
    unsigned short* vnB = knB + 16u*1024u*1024u;             // 32MB

    const float isq = 0.088388347648318447f; // 1/sqrt(128), folded into Wq/bq

    dim3 b256(256);
    dim3 gPrep(36864);
    prep<<<gPrep, b256, 0, stream>>>(Wq, Wk, Wv, Wqt, Wkt, Wvt,
                                     q, k, v, nq_a, nq_b, nk_a, nk_b, nv_a, nv_b,
                                     buf0, knB, vnB, isq);

    dim3 gQKV(768 + 6144);
    dim3 b512(512);
    gemm_qkv<<<gQKV, b512, 0, stream>>>(buf0, knB, vnB, Wqt, Wkt, Wvt,
                                        bq, bk, bv, QtB, KtB, VpB,
                                        Wo, W1, W2, Wot, W1t, W2t, isq);

    dim3 gN(NTOK);
    dim3 gG(256);
    attn_tok<<<gN, b256, 0, stream>>>(QtB, KtB, VpB, buf0);
    gemm256<3><<<gG, b512, 0, stream>>>(buf0, Wot, bo, v, nullptr, nullptr, xb, 0, 1.0f);
    norm_rows_bf16<<<gN, b256, 0, stream>>>(xb, n2_a, n2_b, x2);
    gemm256<1><<<gG, b512, 0, stream>>>(x2, W1t, b1, nullptr, nullptr, nullptr, h1, 0, 1.0f);
    gemm256<4><<<gG, b512, 0, stream>>>(h1, W2t, b2, nullptr, xb, x, nullptr, 0, 1.0f);
}

// Round 15
// 544.259 us; speedup vs baseline: 1.0827x; 1.0827x over previous
//
#include <hip/hip_runtime.h>
#include <hip/hip_bf16.h>

#define DM 2048
#define NTOK 8192
#define EPS 1e-6f

typedef __attribute__((ext_vector_type(8))) short short8;
typedef __attribute__((ext_vector_type(4))) short short4v;
typedef __attribute__((ext_vector_type(4))) float f32x4;
typedef __attribute__((ext_vector_type(16))) float f32x16;
typedef __attribute__((ext_vector_type(4))) unsigned int u32x4;

typedef const __attribute__((address_space(1))) void gvoid;
typedef __attribute__((address_space(3))) void lvoid;

static __device__ __forceinline__ unsigned short f2bf(float f) {
    unsigned u = __builtin_bit_cast(unsigned, f);
    unsigned r = u + 0x7FFFu + ((u >> 16) & 1u);
    return (unsigned short)(r >> 16);
}
static __device__ __forceinline__ float bf2f(unsigned short h) {
    return __builtin_bit_cast(float, (unsigned)h << 16);
}

// ---------------- fused prep: 6 weight transposes + 3 input norms, one flat-grid dispatch
// blocks [0,24576): wtrans z=bx>>12, tile (x=rem&63, y=rem>>6)
// blocks [24576,49152): norm  z=rem>>13, row=rem&8191
__global__ __launch_bounds__(256) void prep(
        const float* __restrict__ Wq, const float* __restrict__ Wk,
        const float* __restrict__ Wv, const float* __restrict__ Wo,
        const float* __restrict__ W1, const float* __restrict__ W2,
        unsigned short* __restrict__ Tq, unsigned short* __restrict__ Tk,
        unsigned short* __restrict__ Tv, unsigned short* __restrict__ To,
        unsigned short* __restrict__ T1, unsigned short* __restrict__ T2,
        const float* __restrict__ q, const float* __restrict__ k,
        const float* __restrict__ v,
        const float* __restrict__ qa, const float* __restrict__ qb,
        const float* __restrict__ ka, const float* __restrict__ kb,
        const float* __restrict__ va, const float* __restrict__ vb,
        unsigned short* __restrict__ oq, unsigned short* __restrict__ ok,
        unsigned short* __restrict__ ov, float isq) {
    const int bx = blockIdx.x;
    const int t = threadIdx.x;
    if (bx < 24576) {
        // ---- weight transpose+cast+scale ----
        __shared__ float tile[32][33];
        const int z = bx >> 12, rem = bx & 4095;
        const float* W = z==0?Wq: z==1?Wk: z==2?Wv: z==3?Wo: z==4?W1: W2;
        unsigned short* Wt = z==0?Tq: z==1?Tk: z==2?Tv: z==3?To: z==4?T1: T2;
        const int perm = (z < 2) ? 1 : 0;
        const float ws = (z == 0) ? isq : 1.0f;
        const int bc = (rem & 63) * 32, bk = (rem >> 6) * 32;
        const int tc = t & 31, tr = t >> 5;
        #pragma unroll
        for (int i = 0; i < 4; ++i)
            tile[tr + i*8][tc] = W[(size_t)(bk + tr + i*8) * DM + bc + tc];
        __syncthreads();
        #pragma unroll
        for (int i = 0; i < 4; ++i) {
            const int c = bc + tr + i*8;
            const int pc = perm ? ((c & 127) * 16 + (c >> 7)) : c;
            Wt[(size_t)pc * DM + bk + tc] = f2bf(tile[tc][tr + i*8] * ws);
        }
    } else {
        // ---- row norm (f32 -> bf16), std ddof=1 ----
        const int rem = bx - 24576;
        const int z = rem >> 13, row = rem & 8191;
        const float* in    = z == 0 ? q  : z == 1 ? k  : v;
        const float* alpha = z == 0 ? qa : z == 1 ? ka : va;
        const float* beta  = z == 0 ? qb : z == 1 ? kb : vb;
        unsigned short* out = z == 0 ? oq : z == 1 ? ok : ov;

        const float* x = in + (size_t)row * DM + t * 8;
        float4 v0 = *(const float4*)(x);
        float4 v1 = *(const float4*)(x + 4);
        float s = (v0.x + v0.y) + (v0.z + v0.w) + (v1.x + v1.y) + (v1.z + v1.w);
        float ss = v0.x*v0.x + v0.y*v0.y + v0.z*v0.z + v0.w*v0.w
                 + v1.x*v1.x + v1.y*v1.y + v1.z*v1.z + v1.w*v1.w;
        #pragma unroll
        for (int m = 1; m < 64; m <<= 1) {
            s  += __shfl_xor(s, m);
            ss += __shfl_xor(ss, m);
        }
        __shared__ float red[8];
        const int wv = t >> 6, ln = t & 63;
        if (ln == 0) { red[wv] = s; red[4 + wv] = ss; }
        __syncthreads();
        s  = (red[0] + red[1]) + (red[2] + red[3]);
        ss = (red[4] + red[5]) + (red[6] + red[7]);
        const float mu = s * (1.0f / DM);
        float var = (ss - s * mu) * (1.0f / (DM - 1));
        var = fmaxf(var, 0.0f);
        const float scale = 1.0f / (sqrtf(var) + EPS);
        float4 a0 = *(const float4*)(alpha + t*8);
        float4 a1 = *(const float4*)(alpha + t*8 + 4);
        float4 b0 = *(const float4*)(beta + t*8);
        float4 b1 = *(const float4*)(beta + t*8 + 4);
        short8 o;
        o[0] = (short)f2bf(a0.x * (v0.x - mu) * scale + b0.x);
        o[1] = (short)f2bf(a0.y * (v0.y - mu) * scale + b0.y);
        o[2] = (short)f2bf(a0.z * (v0.z - mu) * scale + b0.z);
        o[3] = (short)f2bf(a0.w * (v0.w - mu) * scale + b0.w);
        o[4] = (short)f2bf(a1.x * (v1.x - mu) * scale + b1.x);
        o[5] = (short)f2bf(a1.y * (v1.y - mu) * scale + b1.y);
        o[6] = (short)f2bf(a1.z * (v1.z - mu) * scale + b1.z);
        o[7] = (short)f2bf(a1.w * (v1.w - mu) * scale + b1.w);
        *(short8*)(out + (size_t)row * DM + t * 8) = o;
    }
}

// ---------------- row norm (bf16 in) -> bf16 out
__global__ __launch_bounds__(256) void norm_rows_bf16(
        const unsigned short* __restrict__ in, const float* __restrict__ alpha,
        const float* __restrict__ beta, unsigned short* __restrict__ out) {
    const int row = blockIdx.x;
    const int t = threadIdx.x;
    short8 rv = *(const short8*)(in + (size_t)row * DM + t * 8);
    float xv[8];
    #pragma unroll
    for (int j = 0; j < 8; ++j) xv[j] = bf2f((unsigned short)rv[j]);
    float s = 0.f, ss = 0.f;
    #pragma unroll
    for (int j = 0; j < 8; ++j) { s += xv[j]; ss += xv[j]*xv[j]; }
    #pragma unroll
    for (int m = 1; m < 64; m <<= 1) {
        s  += __shfl_xor(s, m);
        ss += __shfl_xor(ss, m);
    }
    __shared__ float red[8];
    const int wv = t >> 6, ln = t & 63;
    if (ln == 0) { red[wv] = s; red[4 + wv] = ss; }
    __syncthreads();
    s  = (red[0] + red[1]) + (red[2] + red[3]);
    ss = (red[4] + red[5]) + (red[6] + red[7]);
    const float mu = s * (1.0f / DM);
    float var = (ss - s * mu) * (1.0f / (DM - 1));
    var = fmaxf(var, 0.0f);
    const float scale = 1.0f / (sqrtf(var) + EPS);
    short8 o;
    #pragma unroll
    for (int j = 0; j < 8; ++j) {
        const float av = alpha[t*8 + j], bv = beta[t*8 + j];
        o[j] = (short)f2bf(av * (xv[j] - mu) * scale + bv);
    }
    *(short8*)(out + (size_t)row * DM + t * 8) = o;
}

// ---------------- 256x256x64 GEMM core (r11 schedule)
#define BARRIER __builtin_amdgcn_s_barrier()
#define WAIT_LGKM0 asm volatile("s_waitcnt lgkmcnt(0)" ::: "memory")
#define VMCNT(n) asm volatile("s_waitcnt vmcnt(" #n ")" ::: "memory")
#define SCHED_FENCE __builtin_amdgcn_sched_barrier(0)

template<int EPI>
__device__ __forceinline__ void gemm_core(
        const unsigned short* __restrict__ A, const unsigned short* __restrict__ Bt,
        const float* __restrict__ bias, const float* __restrict__ residF,
        const unsigned short* __restrict__ residB,
        float* __restrict__ outF, unsigned short* __restrict__ outB, int biasPerm,
        float bscale, int blk) {
    __shared__ __align__(16) char lds[131072];
    char* ldsA = lds;
    char* ldsB = lds + 65536;

    const int t = threadIdx.x, l = t & 63, w = t >> 6;
    const int wm = w >> 2, wn = w & 3;

    const int xcd = blk & 7;
    const int j = blk >> 3;
    const int m0 = (xcd * 4 + (j & 3)) * 256;
    const int n0 = (j >> 2) * 256;

    const int rS = t >> 3;
    const int cS = ((t & 7) ^ (rS & 7)) * 8;
    const unsigned short* aSt = A  + (size_t)(m0 + rS) * 2048 + cS;
    const unsigned short* bSt = Bt + (size_t)(n0 + rS) * 2048 + cS;
    const int ldsStW = w * 1024;

    const int aRd = wm * 16384 + (l & 15) * 128;
    const int bRd = (wn >> 1) * 16384 + (wn & 1) * 8192 + (l & 15) * 128;
    const int ch0 = (((l >> 4) + 0) ^ (l & 7)) * 16;
    const int ch1 = (((l >> 4) + 4) ^ (l & 7)) * 16;

    short8 af[8][2], bf[4][2];
    f32x4 acc[8][4] = {};

#define STG_A(buf, h, kt) do { \
    __builtin_amdgcn_global_load_lds((gvoid*)(aSt + (size_t)((h)*128)*2048 + (kt)*64), \
        (lvoid*)(ldsA + (buf)*32768 + (h)*16384 + ldsStW), 16, 0, 0); \
    __builtin_amdgcn_global_load_lds((gvoid*)(aSt + (size_t)((h)*128+64)*2048 + (kt)*64), \
        (lvoid*)(ldsA + (buf)*32768 + (h)*16384 + 8192 + ldsStW), 16, 0, 0); \
} while(0)
#define STG_B(buf, h, kt) do { \
    __builtin_amdgcn_global_load_lds((gvoid*)(bSt + (size_t)((h)*128)*2048 + (kt)*64), \
        (lvoid*)(ldsB + (buf)*32768 + (h)*16384 + ldsStW), 16, 0, 0); \
    __builtin_amdgcn_global_load_lds((gvoid*)(bSt + (size_t)((h)*128+64)*2048 + (kt)*64), \
        (lvoid*)(ldsB + (buf)*32768 + (h)*16384 + 8192 + ldsStW), 16, 0, 0); \
} while(0)
#define RD_A(buf, mh) do { \
    _Pragma("unroll") for (int ml = 0; ml < 4; ++ml) { \
        af[(mh)*4+ml][0] = *(const short8*)(ldsA + (buf)*32768 + aRd + ((mh)*4+ml)*2048 + ch0); \
        af[(mh)*4+ml][1] = *(const short8*)(ldsA + (buf)*32768 + aRd + ((mh)*4+ml)*2048 + ch1); \
    } } while(0)
#define RD_B(buf, nh) do { \
    _Pragma("unroll") for (int nl = 0; nl < 2; ++nl) { \
        bf[(nh)*2+nl][0] = *(const short8*)(ldsB + (buf)*32768 + bRd + ((nh)*2+nl)*2048 + ch0); \
        bf[(nh)*2+nl][1] = *(const short8*)(ldsB + (buf)*32768 + bRd + ((nh)*2+nl)*2048 + ch1); \
    } } while(0)
#define MM_Q(mh, nh) do { \
    _Pragma("unroll") for (int ml = 0; ml < 4; ++ml) \
    _Pragma("unroll") for (int nl = 0; nl < 2; ++nl) { \
        acc[(mh)*4+ml][(nh)*2+nl] = __builtin_amdgcn_mfma_f32_16x16x32_bf16( \
            af[(mh)*4+ml][0], bf[(nh)*2+nl][0], acc[(mh)*4+ml][(nh)*2+nl], 0, 0, 0); \
        acc[(mh)*4+ml][(nh)*2+nl] = __builtin_amdgcn_mfma_f32_16x16x32_bf16( \
            af[(mh)*4+ml][1], bf[(nh)*2+nl][1], acc[(mh)*4+ml][(nh)*2+nl], 0, 0, 0); \
    } \
} while(0)

    STG_A(0, 0, 0); STG_A(0, 1, 0);
    STG_B(0, 0, 0); STG_B(0, 1, 0);
    STG_A(1, 0, 1); STG_A(1, 1, 1);
    VMCNT(4);
    BARRIER;

    #pragma unroll 1
    for (int i = 0; i < 16; ++i) {
        const int kt1 = 2*i + 1, k2 = 2*i + 2, k3 = 2*i + 3;
        const bool more = (i < 15);
        RD_A(0, 0); RD_A(0, 1); RD_B(0, 0);
        STG_B(1, 0, kt1); STG_B(1, 1, kt1);
        SCHED_FENCE;
        BARRIER; WAIT_LGKM0;
        __builtin_amdgcn_s_setprio(1);
        MM_Q(0, 0); MM_Q(1, 0);
        __builtin_amdgcn_s_setprio(0);
        BARRIER;
        RD_B(0, 1);
        if (more) { STG_A(0, 0, k2); STG_A(0, 1, k2); SCHED_FENCE; VMCNT(4); }
        else { SCHED_FENCE; VMCNT(0); }
        BARRIER; WAIT_LGKM0;
        __builtin_amdgcn_s_setprio(1);
        MM_Q(0, 1); MM_Q(1, 1);
        __builtin_amdgcn_s_setprio(0);
        BARRIER;
        RD_A(1, 0); RD_A(1, 1); RD_B(1, 0);
        if (more) { STG_B(0, 0, k2); STG_B(0, 1, k2); }
        SCHED_FENCE;
        BARRIER; WAIT_LGKM0;
        __builtin_amdgcn_s_setprio(1);
        MM_Q(0, 0); MM_Q(1, 0);
        __builtin_amdgcn_s_setprio(0);
        BARRIER;
        RD_B(1, 1);
        if (more) { STG_A(1, 0, k3); STG_A(1, 1, k3); SCHED_FENCE; VMCNT(4); }
        else { SCHED_FENCE; }
        BARRIER; WAIT_LGKM0;
        __builtin_amdgcn_s_setprio(1);
        MM_Q(0, 1); MM_Q(1, 1);
        __builtin_amdgcn_s_setprio(0);
        BARRIER;
    }

    unsigned short* cs = (unsigned short*)lds;   // [128][260] padded
    #pragma unroll 1
    for (int pass = 0; pass < 2; ++pass) {
        BARRIER;
        if (wm == pass) {
            #pragma unroll
            for (int ni = 0; ni < 4; ++ni) {
                const int col = wn*64 + ni*16 + (l & 15);
                const int gcol = n0 + col;
                const int cb = biasPerm ? ((gcol >> 4) + (gcol & 15) * 128) : gcol;
                const float bvv = bias[cb] * bscale;
                #pragma unroll
                for (int mi = 0; mi < 8; ++mi) {
                    #pragma unroll
                    for (int r = 0; r < 4; ++r) {
                        const int row = mi*16 + (l >> 4)*4 + r;
                        float vv = acc[mi][ni][r] + bvv;
                        if (EPI == 1) vv = fmaxf(vv, 0.0f);
                        cs[row*260 + col] = f2bf(vv);
                    }
                }
            }
        }
        BARRIER;
        #pragma unroll
        for (int s = 0; s < 8; ++s) {
            const int row = (t >> 5) + s*16;
            const int seg = t & 31;
            short8 pk = *(const short8*)(cs + row*260 + seg*8);
            const int grow = m0 + pass*128 + row;
            const size_t gb = (size_t)grow * 2048 + n0 + seg*8;
            if (EPI == 3) {
                float4 r0 = *(const float4*)(residF + gb);
                float4 r1 = *(const float4*)(residF + gb + 4);
                short8 o;
                o[0] = (short)f2bf(bf2f((unsigned short)pk[0]) + r0.x);
                o[1] = (short)f2bf(bf2f((unsigned short)pk[1]) + r0.y);
                o[2] = (short)f2bf(bf2f((unsigned short)pk[2]) + r0.z);
                o[3] = (short)f2bf(bf2f((unsigned short)pk[3]) + r0.w);
                o[4] = (short)f2bf(bf2f((unsigned short)pk[4]) + r1.x);
                o[5] = (short)f2bf(bf2f((unsigned short)pk[5]) + r1.y);
                o[6] = (short)f2bf(bf2f((unsigned short)pk[6]) + r1.z);
                o[7] = (short)f2bf(bf2f((unsigned short)pk[7]) + r1.w);
                *(short8*)(outB + gb) = o;
            } else if (EPI == 4) {
                short8 rb = *(const short8*)(residB + gb);
                float4 o0, o1;
                o0.x = bf2f((unsigned short)pk[0]) + bf2f((unsigned short)rb[0]);
                o0.y = bf2f((unsigned short)pk[1]) + bf2f((unsigned short)rb[1]);
                o0.z = bf2f((unsigned short)pk[2]) + bf2f((unsigned short)rb[2]);
                o0.w = bf2f((unsigned short)pk[3]) + bf2f((unsigned short)rb[3]);
                o1.x = bf2f((unsigned short)pk[4]) + bf2f((unsigned short)rb[4]);
                o1.y = bf2f((unsigned short)pk[5]) + bf2f((unsigned short)rb[5]);
                o1.z = bf2f((unsigned short)pk[6]) + bf2f((unsigned short)rb[6]);
                o1.w = bf2f((unsigned short)pk[7]) + bf2f((unsigned short)rb[7]);
                *(float4*)(outF + gb) = o0;
                *(float4*)(outF + gb + 4) = o1;
            } else {
                *(short8*)(outB + gb) = pk;
            }
        }
    }
#undef STG_A
#undef STG_B
#undef RD_A
#undef RD_B
#undef MM_Q
}

template<int EPI>
__global__ __launch_bounds__(512, 2) void gemm256(
        const unsigned short* __restrict__ A, const unsigned short* __restrict__ Bt,
        const float* __restrict__ bias, const float* __restrict__ residF,
        const unsigned short* __restrict__ residB,
        float* __restrict__ outF, unsigned short* __restrict__ outB, int biasPerm,
        float bscale) {
    gemm_core<EPI>(A, Bt, bias, residF, residB, outF, outB, biasPerm, bscale, blockIdx.x);
}

// fused Q/K/V projection: 768 blocks, z = b>>8 picks stream
__global__ __launch_bounds__(512, 2) void gemm_qkv(
        const unsigned short* __restrict__ Aq, const unsigned short* __restrict__ Ak,
        const unsigned short* __restrict__ Av,
        const unsigned short* __restrict__ Bq, const unsigned short* __restrict__ Bk,
        const unsigned short* __restrict__ Bv,
        const float* __restrict__ bq, const float* __restrict__ bk,
        const float* __restrict__ bv,
        unsigned short* __restrict__ Oq, unsigned short* __restrict__ Ok,
        unsigned short* __restrict__ Ov, float isq) {
    const int z = blockIdx.x >> 8;
    const int blk = blockIdx.x & 255;
    const unsigned short* A  = z == 0 ? Aq : z == 1 ? Ak : Av;
    const unsigned short* Bt = z == 0 ? Bq : z == 1 ? Bk : Bv;
    const float* bias        = z == 0 ? bq : z == 1 ? bk : bv;
    unsigned short* outB     = z == 0 ? Oq : z == 1 ? Ok : Ov;
    const int biasPerm = (z < 2) ? 1 : 0;
    const float bscale = (z == 0) ? isq : 1.0f;
    gemm_core<0>(A, Bt, bias, nullptr, nullptr, nullptr, outB, biasPerm, bscale, blk);
}

// ---------------- per-token attention, fully in-register (swapped QK^T + cvt_pk/permlane)
__global__ __launch_bounds__(256) void attn_tok(
        const unsigned short* __restrict__ Qt, const unsigned short* __restrict__ Kt,
        const unsigned short* __restrict__ Vp, unsigned short* __restrict__ Cc) {
    const int n = blockIdx.x;
    const int t = threadIdx.x, w = t >> 6, l = t & 63;
    const int q31 = l & 31, hi = l >> 5;
    __shared__ __align__(16) unsigned short c_s[16 * 132];

    const size_t tb = (size_t)n * DM;
    const short8 qf = *(const short8*)(Qt + tb + (w*32 + q31)*16 + hi*8);
    short8 kf[4];
    #pragma unroll
    for (int bt = 0; bt < 4; ++bt)
        kf[bt] = *(const short8*)(Kt + tb + (bt*32 + q31)*16 + hi*8);
    short8 vf[8];
    #pragma unroll
    for (int ks = 0; ks < 8; ++ks)
        vf[ks] = *(const short8*)(Vp + tb + (q31 & 15)*128 + ks*16 + hi*8);

    const f32x16 z = {};
    f32x16 sc[4];
    #pragma unroll
    for (int bt = 0; bt < 4; ++bt)
        sc[bt] = __builtin_amdgcn_mfma_f32_32x32x16_bf16(kf[bt], qf, z, 0, 0, 0);

    float m0 = sc[0][0], m1 = sc[1][0], m2 = sc[2][0], m3 = sc[3][0];
    #pragma unroll
    for (int r = 1; r < 16; ++r) {
        m0 = fmaxf(m0, sc[0][r]); m1 = fmaxf(m1, sc[1][r]);
        m2 = fmaxf(m2, sc[2][r]); m3 = fmaxf(m3, sc[3][r]);
    }
    float mx = fmaxf(fmaxf(m0, m1), fmaxf(m2, m3));
    { float a2 = mx, b2 = mx;
      asm volatile("v_permlane32_swap_b32 %0, %1" : "+v"(a2), "+v"(b2));
      mx = fmaxf(a2, b2); }

    float p[4][16];
    float s0 = 0.f, s1 = 0.f, s2 = 0.f, s3 = 0.f;
    #pragma unroll
    for (int r = 0; r < 16; ++r) {
        p[0][r] = __expf(sc[0][r] - mx); s0 += p[0][r];
        p[1][r] = __expf(sc[1][r] - mx); s1 += p[1][r];
        p[2][r] = __expf(sc[2][r] - mx); s2 += p[2][r];
        p[3][r] = __expf(sc[3][r] - mx); s3 += p[3][r];
    }
    float sm = (s0 + s1) + (s2 + s3);
    { float a2 = sm, b2 = sm;
      asm volatile("v_permlane32_swap_b32 %0, %1" : "+v"(a2), "+v"(b2));
      sm = a2 + b2; }
    const float inv = __builtin_amdgcn_rcpf(sm);
    #pragma unroll
    for (int bt = 0; bt < 4; ++bt)
        #pragma unroll
        for (int r = 0; r < 16; ++r)
            p[bt][r] *= inv;

    f32x16 acc = {};
    #pragma unroll
    for (int ks = 0; ks < 8; ++ks) {
        const int bt = ks >> 1, r0 = (ks & 1) * 8;
        unsigned X0, Y0, X1, Y1;
        asm("v_cvt_pk_bf16_f32 %0, %1, %2" : "=v"(X0) : "v"(p[bt][r0+0]), "v"(p[bt][r0+1]));
        asm("v_cvt_pk_bf16_f32 %0, %1, %2" : "=v"(Y0) : "v"(p[bt][r0+4]), "v"(p[bt][r0+5]));
        asm("v_cvt_pk_bf16_f32 %0, %1, %2" : "=v"(X1) : "v"(p[bt][r0+2]), "v"(p[bt][r0+3]));
        asm("v_cvt_pk_bf16_f32 %0, %1, %2" : "=v"(Y1) : "v"(p[bt][r0+6]), "v"(p[bt][r0+7]));
        asm volatile("v_permlane32_swap_b32 %0, %1" : "+v"(X0), "+v"(Y0));
        asm volatile("v_permlane32_swap_b32 %0, %1" : "+v"(X1), "+v"(Y1));
        u32x4 pw; pw[0] = X0; pw[1] = X1; pw[2] = Y0; pw[3] = Y1;
        const short8 paf = __builtin_bit_cast(short8, pw);
        acc = __builtin_amdgcn_mfma_f32_32x32x16_bf16(paf, vf[ks], acc, 0, 0, 0);
    }

    if (q31 < 16) {
        #pragma unroll
        for (int rp = 0; rp < 8; ++rp) {
            const int r = rp * 2;
            const int a = (r & 3) + 8 * (r >> 2) + 4 * hi;
            unsigned pk;
            asm("v_cvt_pk_bf16_f32 %0, %1, %2" : "=v"(pk) : "v"(acc[r]), "v"(acc[r+1]));
            *(unsigned*)((char*)c_s + q31*264 + (w*32 + a)*2) = pk;
        }
    }
    __syncthreads();
    *(short8*)(Cc + tb + t*8) = *(const short8*)((char*)c_s + (t >> 4)*264 + (t & 15)*16);
}

extern "C" void kernel_launch(void* const* d_in, const int* in_sizes, int n_in,
                              void* d_out, int out_size, void* d_ws, size_t ws_size,
                              hipStream_t stream) {
    (void)in_sizes; (void)n_in; (void)out_size; (void)ws_size;
    const float* q    = (const float*)d_in[0];
    const float* k    = (const float*)d_in[1];
    const float* v    = (const float*)d_in[2];
    const float* nq_a = (const float*)d_in[3];
    const float* nq_b = (const float*)d_in[4];
    const float* nk_a = (const float*)d_in[5];
    const float* nk_b = (const float*)d_in[6];
    const float* nv_a = (const float*)d_in[7];
    const float* nv_b = (const float*)d_in[8];
    const float* n2_a = (const float*)d_in[9];
    const float* n2_b = (const float*)d_in[10];
    const float* Wq   = (const float*)d_in[11];
    const float* bq   = (const float*)d_in[12];
    const float* Wk   = (const float*)d_in[13];
    const float* bk   = (const float*)d_in[14];
    const float* Wv   = (const float*)d_in[15];
    const float* bv   = (const float*)d_in[16];
    const float* Wo   = (const float*)d_in[17];
    const float* bo   = (const float*)d_in[18];
    const float* W1   = (const float*)d_in[19];
    const float* b1   = (const float*)d_in[20];
    const float* W2   = (const float*)d_in[21];
    const float* b2   = (const float*)d_in[22];

    char* ws = (char*)d_ws;
    const size_t MB = 1024 * 1024;
    unsigned short* buf0 = (unsigned short*)(ws);            // qn, later concat
    unsigned short* QtB  = (unsigned short*)(ws + 32*MB);
    unsigned short* KtB  = (unsigned short*)(ws + 64*MB);
    unsigned short* VpB  = (unsigned short*)(ws + 96*MB);
    unsigned short* Wqt  = (unsigned short*)(ws + 128*MB);
    unsigned short* Wkt  = (unsigned short*)(ws + 136*MB);
    unsigned short* Wvt  = (unsigned short*)(ws + 144*MB);
    unsigned short* Wot  = (unsigned short*)(ws + 152*MB);
    unsigned short* W1t  = (unsigned short*)(ws + 160*MB);
    unsigned short* W2t  = (unsigned short*)(ws + 168*MB);
    unsigned short* x2   = QtB;   // after Q consumed
    unsigned short* h1   = KtB;   // after K consumed
    unsigned short* xb   = VpB;   // bf16 residual stream, after V consumed
    float* x = (float*)d_out;     // final f32 output
    // d_out (64MB) doubles as kn/vn scratch until FF2's final write
    unsigned short* knB = (unsigned short*)d_out;            // 32MB
    unsigned short* vnB = knB + 16u*1024u*1024u;             // 32MB

    const float isq = 0.088388347648318447f; // 1/sqrt(128), folded into Wq/bq

    dim3 b256(256);
    dim3 gPrep(49152);
    prep<<<gPrep, b256, 0, stream>>>(Wq, Wk, Wv, Wo, W1, W2,
                                     Wqt, Wkt, Wvt, Wot, W1t, W2t,
                                     q, k, v, nq_a, nq_b, nk_a, nk_b, nv_a, nv_b,
                                     buf0, knB, vnB, isq);

    dim3 gQKV(768);
    dim3 b512(512);
    gemm_qkv<<<gQKV, b512, 0, stream>>>(buf0, knB, vnB, Wqt, Wkt, Wvt,
                                        bq, bk, bv, QtB, KtB, VpB, isq);

    dim3 gN(NTOK);
    dim3 gG(256);
    attn_tok<<<gN, b256, 0, stream>>>(QtB, KtB, VpB, buf0);
    gemm256<3><<<gG, b512, 0, stream>>>(buf0, Wot, bo, v, nullptr, nullptr, xb, 0, 1.0f);
    norm_rows_bf16<<<gN, b256, 0, stream>>>(xb, n2_a, n2_b, x2);
    gemm256<1><<<gG, b512, 0, stream>>>(x2, W1t, b1, nullptr, nullptr, nullptr, h1, 0, 1.0f);
    gemm256<4><<<gG, b512, 0, stream>>>(h1, W2t, b2, nullptr, xb, x, nullptr, 0, 1.0f);
}